// Round 4
// baseline (23.735 us; speedup 1.0000x reference)
//
#include <hip/hip_runtime.h>
#include <math.h>

// ---------------------------------------------------------------------------
// TripletLossAttribute — fused, one 516B memset + one kernel.
//   seg(k): k in [341*d, 341*(d+1)) for d<5, seg5 = [1705, 2048)
//   sq[i,j] = sum_k a2[i,j,seg(k)] * (x_j[k]-x_i[k])^2 ; dist = sqrt(max(sq,1e-12))
//   ap[i] = max_{t_j==t_i} dist;  an[i] = min_{t_j!=t_i} dist
//   loss = mean(relu(ap - an + 0.3))
//
// Grid: 256 blocks x 1024 threads (16 waves). Block b: row i=b>>2, columns
// j = (b&3)*16 + wave. ONE PAIR PER WAVE -> 4096 waves total (4/SIMD, full
// TLP — round 3's regression was dropping to 1 wave/SIMD).
//
// Cross-block reduction via order-independent uint atomics on nonneg floats:
//   an[i]     = atomicMin over  bits(dist)   (uint compare == float compare)
//   ap[i](max)= atomicMin over ~bits(dist)   (NOT flips the order)
// Both init = 0xFFFFFFFF -> a single memset(0xFF) re-inits everything per
// graph replay. Arrival counter also starts 0xFFFFFFFF; after n atomicAdds
// old value = n-2 (wrap), so the 256th arrival sees old == 254.
//
// ws layout (uint words): [0..63] an_bits, [64..127] apkey_bits, [128] counter.
// ---------------------------------------------------------------------------

__global__ __launch_bounds__(1024) void triplet_fused(
    const float*    __restrict__ x,     // 64 x 2048
    const int*      __restrict__ tgt,   // 64
    const float*    __restrict__ attr,  // 64 x 64 x 6
    float*          __restrict__ out,   // 1
    unsigned int*   __restrict__ ws)    // see layout
{
    const int b    = blockIdx.x;
    const int i    = b >> 2;
    const int jc   = b & 3;
    const int wave = threadIdx.x >> 6;     // 0..15
    const int lane = threadIdx.x & 63;
    const int j    = jc * 16 + wave;       // this wave's column

    __shared__ float sm[16];
    __shared__ int   s_last;

    const float4* __restrict__ xi = (const float4*)(x + i * 2048);
    const float4* __restrict__ xj = (const float4*)(x + j * 2048);
    const float*  __restrict__ a  = attr + (i * 64 + j) * 6;

    const float a20 = a[0] * a[0];
    const float a21 = a[1] * a[1];
    const float a22 = a[2] * a[2];
    const float a23 = a[3] * a[3];
    const float a24 = a[4] * a[4];
    const float a25 = a[5] * a[5];

    float acc = 0.f;

    // step crossing one segment boundary B: one cmp+select per element
#define STEP_B(T, WLO, WHI, B)                                               \
    {                                                                        \
        const int c  = (T) * 64 + lane;                                      \
        const int k0 = c * 4;                                                \
        float4 vi = xi[c];                                                   \
        float4 vj = xj[c];                                                   \
        float dx;                                                            \
        dx = vj.x - vi.x; acc = fmaf(dx * dx, (k0 + 0 < (B)) ? (WLO) : (WHI), acc); \
        dx = vj.y - vi.y; acc = fmaf(dx * dx, (k0 + 1 < (B)) ? (WLO) : (WHI), acc); \
        dx = vj.z - vi.z; acc = fmaf(dx * dx, (k0 + 2 < (B)) ? (WLO) : (WHI), acc); \
        dx = vj.w - vi.w; acc = fmaf(dx * dx, (k0 + 3 < (B)) ? (WLO) : (WHI), acc); \
    }
    // step entirely inside one segment: no select
#define STEP_U(T, W)                                                         \
    {                                                                        \
        const int c = (T) * 64 + lane;                                       \
        float4 vi = xi[c];                                                   \
        float4 vj = xj[c];                                                   \
        float dx;                                                            \
        dx = vj.x - vi.x; acc = fmaf(dx * dx, (W), acc);                     \
        dx = vj.y - vi.y; acc = fmaf(dx * dx, (W), acc);                     \
        dx = vj.z - vi.z; acc = fmaf(dx * dx, (W), acc);                     \
        dx = vj.w - vi.w; acc = fmaf(dx * dx, (W), acc);                     \
    }

    STEP_U(0, a20);                 // [0,256)     seg0
    STEP_B(1, a20, a21, 341);       // [256,512)   seg0|1
    STEP_B(2, a21, a22, 682);       // [512,768)   seg1|2
    STEP_B(3, a22, a23, 1023);      // [768,1024)  seg2|3
    STEP_U(4, a23);                 // [1024,1280) seg3
    STEP_B(5, a23, a24, 1364);      // [1280,1536) seg3|4
    STEP_B(6, a24, a25, 1705);      // [1536,1792) seg4|5
    STEP_U(7, a25);                 // [1792,2048) seg5
#undef STEP_B
#undef STEP_U

#pragma unroll
    for (int off = 32; off; off >>= 1) acc += __shfl_xor(acc, off);

    if (lane == 0) sm[wave] = sqrtf(fmaxf(acc, 1e-12f));

    __syncthreads();

    // lanes 0..15 of wave 0: masked 16-wide reduce, then 2 atomics + fence
    if (threadIdx.x < 16) {
        const int   jj  = jc * 16 + threadIdx.x;
        const float d   = sm[threadIdx.x];
        const bool  pos = (tgt[jj] == tgt[i]);
        float apv = pos ? d : -INFINITY;    // max over positives
        float anv = pos ? INFINITY : d;     // min over negatives
#pragma unroll
        for (int off = 8; off; off >>= 1) {
            apv = fmaxf(apv, __shfl_xor(apv, off));
            anv = fminf(anv, __shfl_xor(anv, off));
        }
        if (threadIdx.x == 0) {
            // encode as uint-min keys (dist >= 0 so bit order == float order);
            // -inf/+inf partials encode to all-ones-ish keys that never win
            if (apv >= 0.f) atomicMin(&ws[64 + i], ~__float_as_uint(apv));
            if (anv < INFINITY) atomicMin(&ws[i], __float_as_uint(anv));
            __threadfence();   // release partials before arrival
            const unsigned old = atomicAdd(&ws[128], 1u);
            s_last = (old == 254u) ? 1 : 0;   // counter started 0xFFFFFFFF
        }
    }
    __syncthreads();

    if (s_last) {
        __threadfence();   // acquire all blocks' partials
        if (threadIdx.x < 64) {
            const int r = threadIdx.x;
            const unsigned anb = __hip_atomic_load(&ws[r], __ATOMIC_RELAXED,
                                                   __HIP_MEMORY_SCOPE_AGENT);
            const unsigned apk = __hip_atomic_load(&ws[64 + r], __ATOMIC_RELAXED,
                                                   __HIP_MEMORY_SCOPE_AGENT);
            const float ap = __uint_as_float(~apk);
            const float an = __uint_as_float(anb);   // 0xFFFFFFFF (never) -> NaN,
                                                     // impossible: every row has negs
            float term = fmaxf(ap - an + 0.3f, 0.f);
#pragma unroll
            for (int off = 32; off; off >>= 1) term += __shfl_xor(term, off);
            if (r == 0) out[0] = term * (1.0f / 64.0f);
        }
    }
}

extern "C" void kernel_launch(void* const* d_in, const int* in_sizes, int n_in,
                              void* d_out, int out_size, void* d_ws, size_t ws_size,
                              hipStream_t stream) {
    const float* x    = (const float*)d_in[0];   // inputs (64,2048) f32
    const int*   tgt  = (const int*)d_in[1];     // targets (64,) i32
    const float* attr = (const float*)d_in[2];   // attention (64,64,6) f32
    float* out = (float*)d_out;
    unsigned int* ws = (unsigned int*)d_ws;

    // single init: an/apkey/counter all want 0xFFFFFFFF (129 words = 516 B)
    hipMemsetAsync(d_ws, 0xFF, 516, stream);
    triplet_fused<<<256, 1024, 0, stream>>>(x, tgt, attr, out, ws);
}

// Round 5
// 13.824 us; speedup vs baseline: 1.7169x; 1.7169x over previous
//
#include <hip/hip_runtime.h>
#include <math.h>

// ---------------------------------------------------------------------------
// TripletLossAttribute — two kernels (round-2 structure, best so far), with
// kernel1 computing BOTH directed pairs (i,j) and (j,i) per wave:
//   sq[i,j] = sum_k a2[i,j,seg(k)] * (x_i[k]-x_j[k])^2  — the (x_i-x_j)^2
//   terms are shared between (i,j) and (j,i); only weights differ. This
//   halves x L2-traffic (64MB -> 32MB) and amortizes sub+mul per element.
// To keep 4096 waves (4/SIMD TLP — round 3 showed dropping this is fatal),
// each wave handles HALF of k (1024 elems); kernel2 sums the two halves.
//
// Pair coverage: p in [0,2048): i = p&63, j = (i + 1 + (p>>6)) & 63 covers
// every unordered pair; d=32 pairs are generated twice — both waves compute
// bit-identical values (dx^2 == (-dx)^2 exactly), benign double-write.
// Diagonal: never computed; kernel2 uses dist(i,i) = 1e-6 analytically
// (= sqrt(clip(0, 1e-12)), exact vs reference).
//
// seg(k): k in [341*d, 341*(d+1)) for d<5, seg5 = [1705,2048). Each 256-wide
// chunk crosses at most one boundary -> one const-compare select per element.
//
// ws layout: float pd[2][4096] — k-half partial sums (pre-sqrt).
// ---------------------------------------------------------------------------

__global__ __launch_bounds__(256) void pair_dist_kernel(
    const float* __restrict__ x,     // 64 x 2048
    const float* __restrict__ attr,  // 64 x 64 x 6
    float* __restrict__ pd)          // [2][64][64] partial sq-sums
{
    const int w    = blockIdx.x * 4 + (threadIdx.x >> 6);  // 0..4095
    const int lane = threadIdx.x & 63;
    const int h    = w & 1;            // k-half
    const int p    = w >> 1;           // 0..2047
    const int i    = p & 63;
    const int dd   = 1 + (p >> 6);     // 1..32
    const int j    = (i + dd) & 63;

    const float4* __restrict__ xi = (const float4*)(x + i * 2048);
    const float4* __restrict__ xj = (const float4*)(x + j * 2048);
    // attr rows are 24B -> float2 aligned
    const float2* __restrict__ aij = (const float2*)(attr + (i * 64 + j) * 6);
    const float2* __restrict__ aji = (const float2*)(attr + (j * 64 + i) * 6);

    const float2 bA = aij[0], bB = aij[1], bC = aij[2];
    const float2 cA = aji[0], cB = aji[1], cC = aji[2];
    const float b0 = bA.x * bA.x, b1 = bA.y * bA.y, b2 = bB.x * bB.x,
                b3 = bB.y * bB.y, b4 = bC.x * bC.x, b5 = bC.y * bC.y;
    const float c0 = cA.x * cA.x, c1 = cA.y * cA.y, c2 = cB.x * cB.x,
                c3 = cB.y * cB.y, c4 = cC.x * cC.x, c5 = cC.y * cC.y;

    float accI = 0.f, accJ = 0.f;   // (i,j)-weighted and (j,i)-weighted

    // chunk fully inside one segment: dx^2 once, two weighted fmas
#define STEP_U2(T, WI, WJ)                                                    \
    {                                                                         \
        float4 vi = xi[(T) * 64 + lane], vj = xj[(T) * 64 + lane];            \
        float dx, d2;                                                         \
        dx = vj.x - vi.x; d2 = dx * dx; accI = fmaf(d2, (WI), accI); accJ = fmaf(d2, (WJ), accJ); \
        dx = vj.y - vi.y; d2 = dx * dx; accI = fmaf(d2, (WI), accI); accJ = fmaf(d2, (WJ), accJ); \
        dx = vj.z - vi.z; d2 = dx * dx; accI = fmaf(d2, (WI), accI); accJ = fmaf(d2, (WJ), accJ); \
        dx = vj.w - vi.w; d2 = dx * dx; accI = fmaf(d2, (WI), accI); accJ = fmaf(d2, (WJ), accJ); \
    }
    // chunk crossing boundary B: shared compare, two selected weights
#define STEP_B2(T, WIL, WIH, WJL, WJH, B)                                     \
    {                                                                         \
        const int k0 = ((T) * 64 + lane) * 4;                                 \
        float4 vi = xi[(T) * 64 + lane], vj = xj[(T) * 64 + lane];            \
        float dx, d2; bool lo;                                                \
        dx = vj.x - vi.x; d2 = dx * dx; lo = (k0 + 0 < (B));                  \
        accI = fmaf(d2, lo ? (WIL) : (WIH), accI); accJ = fmaf(d2, lo ? (WJL) : (WJH), accJ); \
        dx = vj.y - vi.y; d2 = dx * dx; lo = (k0 + 1 < (B));                  \
        accI = fmaf(d2, lo ? (WIL) : (WIH), accI); accJ = fmaf(d2, lo ? (WJL) : (WJH), accJ); \
        dx = vj.z - vi.z; d2 = dx * dx; lo = (k0 + 2 < (B));                  \
        accI = fmaf(d2, lo ? (WIL) : (WIH), accI); accJ = fmaf(d2, lo ? (WJL) : (WJH), accJ); \
        dx = vj.w - vi.w; d2 = dx * dx; lo = (k0 + 3 < (B));                  \
        accI = fmaf(d2, lo ? (WIL) : (WIH), accI); accJ = fmaf(d2, lo ? (WJL) : (WJH), accJ); \
    }

    if (h == 0) {                        // k in [0,1024)
        STEP_U2(0, b0, c0);              // [0,256)     seg0
        STEP_B2(1, b0, b1, c0, c1, 341); // [256,512)   seg0|1
        STEP_B2(2, b1, b2, c1, c2, 682); // [512,768)   seg1|2
        STEP_B2(3, b2, b3, c2, c3, 1023);// [768,1024)  seg2|3
    } else {                             // k in [1024,2048)
        STEP_U2(4, b3, c3);              // [1024,1280) seg3
        STEP_B2(5, b3, b4, c3, c4, 1364);// [1280,1536) seg3|4
        STEP_B2(6, b4, b5, c4, c5, 1705);// [1536,1792) seg4|5
        STEP_U2(7, b5, c5);              // [1792,2048) seg5
    }
#undef STEP_U2
#undef STEP_B2

    // two independent 64-lane butterfly sums (interleaved for ILP)
#pragma unroll
    for (int off = 32; off; off >>= 1) {
        accI += __shfl_xor(accI, off);
        accJ += __shfl_xor(accJ, off);
    }

    if (lane == 0) {
        pd[h * 4096 + i * 64 + j] = accI;
        pd[h * 4096 + j * 64 + i] = accJ;
    }
}

// 1 block, 16 waves; wave handles 4 rows: sum halves -> sqrt -> masked
// max/min reduce; then wave 0 means the 64 relu terms.
__global__ __launch_bounds__(1024) void loss_kernel(
    const float* __restrict__ pd,    // [2][64][64]
    const int*   __restrict__ tgt,   // 64
    float*       __restrict__ out)   // 1
{
    __shared__ float terms[64];
    const int lane = threadIdx.x & 63;
    const int wave = threadIdx.x >> 6;   // 0..15
    const int r0   = wave * 4;
    const int tl   = tgt[lane];

    // issue all loads up-front
    float s0 = pd[(r0 + 0) * 64 + lane] + pd[4096 + (r0 + 0) * 64 + lane];
    float s1 = pd[(r0 + 1) * 64 + lane] + pd[4096 + (r0 + 1) * 64 + lane];
    float s2 = pd[(r0 + 2) * 64 + lane] + pd[4096 + (r0 + 2) * 64 + lane];
    float s3 = pd[(r0 + 3) * 64 + lane] + pd[4096 + (r0 + 3) * 64 + lane];

#define ROW_REDUCE(RR, SV)                                                    \
    {                                                                         \
        const int tr = tgt[RR];                                               \
        /* diagonal never written by kernel1 (poison) -> analytic 1e-6 */     \
        float dj = ((RR) == lane) ? 1e-6f : sqrtf(fmaxf((SV), 1e-12f));       \
        bool pos = (tr == tl);                                                \
        float ap = pos ? dj : -INFINITY;                                      \
        float an = pos ? INFINITY : dj;                                       \
        _Pragma("unroll")                                                     \
        for (int off = 32; off; off >>= 1) {                                  \
            ap = fmaxf(ap, __shfl_xor(ap, off));                              \
            an = fminf(an, __shfl_xor(an, off));                              \
        }                                                                     \
        if (lane == 0) terms[RR] = fmaxf(ap - an + 0.3f, 0.f);                \
    }
    ROW_REDUCE(r0 + 0, s0);
    ROW_REDUCE(r0 + 1, s1);
    ROW_REDUCE(r0 + 2, s2);
    ROW_REDUCE(r0 + 3, s3);
#undef ROW_REDUCE

    __syncthreads();

    if (threadIdx.x < 64) {
        float v = terms[threadIdx.x];
#pragma unroll
        for (int off = 32; off; off >>= 1) v += __shfl_xor(v, off);
        if (threadIdx.x == 0) out[0] = v * (1.0f / 64.0f);
    }
}

extern "C" void kernel_launch(void* const* d_in, const int* in_sizes, int n_in,
                              void* d_out, int out_size, void* d_ws, size_t ws_size,
                              hipStream_t stream) {
    const float* x    = (const float*)d_in[0];   // inputs (64,2048) f32
    const int*   tgt  = (const int*)d_in[1];     // targets (64,) i32
    const float* attr = (const float*)d_in[2];   // attention (64,64,6) f32
    float* out = (float*)d_out;
    float* pd  = (float*)d_ws;                   // 8192 floats

    pair_dist_kernel<<<1024, 256, 0, stream>>>(x, attr, pd);
    loss_kernel<<<1, 1024, 0, stream>>>(pd, tgt, out);
}

// Round 6
// 12.510 us; speedup vs baseline: 1.8973x; 1.1051x over previous
//
#include <hip/hip_runtime.h>
#include <math.h>

// ---------------------------------------------------------------------------
// TripletLossAttribute — two kernels (empirically the right structure: any
// in-kernel cross-XCD reduction costs more than a kernel boundary on MI355X).
//
// kernel1 (round-5 math): wave computes BOTH directed pairs (i,j),(j,i) over
// HALF of k (shares (xi-xj)^2, halves x traffic, keeps 4096 waves = 4/SIMD).
// Pair map: p in [0,2048): i=p&63, j=(i+1+(p>>6))&63; d=32 double-writes are
// bit-identical. Diagonal handled analytically in kernel2 (dist=1e-6).
// seg(k) boundaries 341,682,1023,1364,1705: each 256-wide chunk crosses at
// most one -> one const-compare select per element.
//
// kernel2: short critical path — one float4 load per half per thread,
// in-lane 4-wide minmax, 4-level 16-lane butterfly, then 64-term mean.
//
// ws layout: float pd[2][64][64] — k-half partial sq-sums (pre-sqrt).
// ---------------------------------------------------------------------------

__global__ __launch_bounds__(512) void pair_dist_kernel(
    const float* __restrict__ x,     // 64 x 2048
    const float* __restrict__ attr,  // 64 x 64 x 6
    float* __restrict__ pd)          // [2][64][64]
{
    const int w    = blockIdx.x * 8 + (threadIdx.x >> 6);  // 0..4095
    const int lane = threadIdx.x & 63;
    const int h    = w & 1;            // k-half
    const int p    = w >> 1;           // 0..2047
    const int i    = p & 63;
    const int dd   = 1 + (p >> 6);     // 1..32
    const int j    = (i + dd) & 63;

    const float4* __restrict__ xi = (const float4*)(x + i * 2048);
    const float4* __restrict__ xj = (const float4*)(x + j * 2048);
    const float2* __restrict__ aij = (const float2*)(attr + (i * 64 + j) * 6);
    const float2* __restrict__ aji = (const float2*)(attr + (j * 64 + i) * 6);

    const float2 bA = aij[0], bB = aij[1], bC = aij[2];
    const float2 cA = aji[0], cB = aji[1], cC = aji[2];
    const float b0 = bA.x * bA.x, b1 = bA.y * bA.y, b2 = bB.x * bB.x,
                b3 = bB.y * bB.y, b4 = bC.x * bC.x, b5 = bC.y * bC.y;
    const float c0 = cA.x * cA.x, c1 = cA.y * cA.y, c2 = cB.x * cB.x,
                c3 = cB.y * cB.y, c4 = cC.x * cC.x, c5 = cC.y * cC.y;

    float accI = 0.f, accJ = 0.f;

#define STEP_U2(T, WI, WJ)                                                    \
    {                                                                         \
        float4 vi = xi[(T) * 64 + lane], vj = xj[(T) * 64 + lane];            \
        float dx, d2;                                                         \
        dx = vj.x - vi.x; d2 = dx * dx; accI = fmaf(d2, (WI), accI); accJ = fmaf(d2, (WJ), accJ); \
        dx = vj.y - vi.y; d2 = dx * dx; accI = fmaf(d2, (WI), accI); accJ = fmaf(d2, (WJ), accJ); \
        dx = vj.z - vi.z; d2 = dx * dx; accI = fmaf(d2, (WI), accI); accJ = fmaf(d2, (WJ), accJ); \
        dx = vj.w - vi.w; d2 = dx * dx; accI = fmaf(d2, (WI), accI); accJ = fmaf(d2, (WJ), accJ); \
    }
#define STEP_B2(T, WIL, WIH, WJL, WJH, B)                                     \
    {                                                                         \
        const int k0 = ((T) * 64 + lane) * 4;                                 \
        float4 vi = xi[(T) * 64 + lane], vj = xj[(T) * 64 + lane];            \
        float dx, d2; bool lo;                                                \
        dx = vj.x - vi.x; d2 = dx * dx; lo = (k0 + 0 < (B));                  \
        accI = fmaf(d2, lo ? (WIL) : (WIH), accI); accJ = fmaf(d2, lo ? (WJL) : (WJH), accJ); \
        dx = vj.y - vi.y; d2 = dx * dx; lo = (k0 + 1 < (B));                  \
        accI = fmaf(d2, lo ? (WIL) : (WIH), accI); accJ = fmaf(d2, lo ? (WJL) : (WJH), accJ); \
        dx = vj.z - vi.z; d2 = dx * dx; lo = (k0 + 2 < (B));                  \
        accI = fmaf(d2, lo ? (WIL) : (WIH), accI); accJ = fmaf(d2, lo ? (WJL) : (WJH), accJ); \
        dx = vj.w - vi.w; d2 = dx * dx; lo = (k0 + 3 < (B));                  \
        accI = fmaf(d2, lo ? (WIL) : (WIH), accI); accJ = fmaf(d2, lo ? (WJL) : (WJH), accJ); \
    }

    if (h == 0) {                        // k in [0,1024)
        STEP_U2(0, b0, c0);
        STEP_B2(1, b0, b1, c0, c1, 341);
        STEP_B2(2, b1, b2, c1, c2, 682);
        STEP_B2(3, b2, b3, c2, c3, 1023);
    } else {                             // k in [1024,2048)
        STEP_U2(4, b3, c3);
        STEP_B2(5, b3, b4, c3, c4, 1364);
        STEP_B2(6, b4, b5, c4, c5, 1705);
        STEP_U2(7, b5, c5);
    }
#undef STEP_U2
#undef STEP_B2

#pragma unroll
    for (int off = 32; off; off >>= 1) {
        accI += __shfl_xor(accI, off);
        accJ += __shfl_xor(accJ, off);
    }

    if (lane == 0) {
        pd[h * 4096 + i * 64 + j] = accI;
        pd[h * 4096 + j * 64 + i] = accJ;
    }
}

// 1 block x 1024: thread t owns row r=t>>4, cols c0=(t&15)*4 .. +3.
__global__ __launch_bounds__(1024) void loss_kernel(
    const float* __restrict__ pd,    // [2][64][64]
    const int*   __restrict__ tgt,   // 64
    float*       __restrict__ out)   // 1
{
    __shared__ float terms[64];
    const int t  = threadIdx.x;
    const int r  = t >> 4;
    const int c0 = (t & 15) * 4;

    const float4* __restrict__ pd4 = (const float4*)pd;
    const float4 lo = pd4[t];          // half 0, row r, cols c0..c0+3
    const float4 hi = pd4[1024 + t];   // half 1
    const int    tr = tgt[r];

    float ap = -INFINITY, an = INFINITY;
#define ELEM(SC, C)                                                           \
    {                                                                         \
        const int c = (C);                                                    \
        float d = (c == r) ? 1e-6f : sqrtf(fmaxf((SC), 1e-12f));              \
        if (tgt[c] == tr) ap = fmaxf(ap, d); else an = fminf(an, d);          \
    }
    ELEM(lo.x + hi.x, c0 + 0);
    ELEM(lo.y + hi.y, c0 + 1);
    ELEM(lo.z + hi.z, c0 + 2);
    ELEM(lo.w + hi.w, c0 + 3);
#undef ELEM

    // 16-lane butterfly (xor 1,2,4,8 stays within the aligned 16-group)
#pragma unroll
    for (int off = 8; off; off >>= 1) {
        ap = fmaxf(ap, __shfl_xor(ap, off));
        an = fminf(an, __shfl_xor(an, off));
    }
    if ((t & 15) == 0) terms[r] = fmaxf(ap - an + 0.3f, 0.f);

    __syncthreads();

    if (t < 64) {
        float v = terms[t];
#pragma unroll
        for (int off = 32; off; off >>= 1) v += __shfl_xor(v, off);
        if (t == 0) out[0] = v * (1.0f / 64.0f);
    }
}

extern "C" void kernel_launch(void* const* d_in, const int* in_sizes, int n_in,
                              void* d_out, int out_size, void* d_ws, size_t ws_size,
                              hipStream_t stream) {
    const float* x    = (const float*)d_in[0];   // inputs (64,2048) f32
    const int*   tgt  = (const int*)d_in[1];     // targets (64,) i32
    const float* attr = (const float*)d_in[2];   // attention (64,64,6) f32
    float* out = (float*)d_out;
    float* pd  = (float*)d_ws;                   // 8192 floats

    pair_dist_kernel<<<512, 512, 0, stream>>>(x, attr, pd);
    loss_kernel<<<1, 1024, 0, stream>>>(pd, tgt, out);
}